// Round 1
// baseline (1692.799 us; speedup 1.0000x reference)
//
#include <hip/hip_runtime.h>
#include <cstdint>

#define EPSF 1e-5f

// Problem constants (from reference): K=27 offsets, NI=32, NF=64, I=8 interp taps.
constexpr int KOFF = 27;

// ---------------------------------------------------------------------------
// Per-channel sum / sumsq over rows (training-mode BN stats).
// v: [n, C] row-major. out: [2*C] (sums, then sumsqs). Must be pre-zeroed.
// ---------------------------------------------------------------------------
template <int C>
__global__ __launch_bounds__(256) void stats_k(const float* __restrict__ v, int n,
                                               float* __restrict__ out) {
    __shared__ float ls[2 * 256];
    const int c   = threadIdx.x % C;
    const int rpb = 256 / C;
    int r0     = blockIdx.x * rpb + threadIdx.x / C;
    int stride = gridDim.x * rpb;
    float s = 0.f, ss = 0.f;
    for (int r = r0; r < n; r += stride) {
        float x = v[(size_t)r * C + c];
        s += x;
        ss += x * x;
    }
    ls[threadIdx.x]       = s;
    ls[256 + threadIdx.x] = ss;
    __syncthreads();
    for (int off = 128; off >= C; off >>= 1) {
        if (threadIdx.x < off) {
            ls[threadIdx.x] += ls[threadIdx.x + off];
            ls[256 + threadIdx.x] += ls[256 + threadIdx.x + off];
        }
        __syncthreads();
    }
    if (threadIdx.x < C) {
        atomicAdd(&out[threadIdx.x], ls[threadIdx.x]);
        atomicAdd(&out[C + threadIdx.x], ls[256 + threadIdx.x]);
    }
}

// ---------------------------------------------------------------------------
// Gather conv: out[n][o] = sum_{k,i} feats[nbr[n*27+k]][i] * W[k][i][o]
// One thread per row n, 64 accumulators in registers. Weight indices are
// wave-uniform -> scalar loads.
// ---------------------------------------------------------------------------
template <int CIN>
__global__ __launch_bounds__(256) void conv_k(const float* __restrict__ feats,
                                              const int* __restrict__ nbr,
                                              const float* __restrict__ W,
                                              float* __restrict__ out, int N) {
    int n = blockIdx.x * 256 + threadIdx.x;
    if (n >= N) return;
    float acc[64];
#pragma unroll
    for (int o = 0; o < 64; ++o) acc[o] = 0.f;

    const int* nb = nbr + (size_t)n * KOFF;
    for (int k = 0; k < KOFF; ++k) {
        int idx           = nb[k];
        const float4* xr  = (const float4*)(feats + (size_t)idx * CIN);
        const float* wk   = W + (size_t)k * CIN * 64;
        for (int i4 = 0; i4 < CIN / 4; ++i4) {
            float4 xv        = xr[i4];
            const float* wr  = wk + i4 * 4 * 64;
#pragma unroll
            for (int j = 0; j < 4; ++j) {
                float xs = (&xv.x)[j];
#pragma unroll
                for (int o = 0; o < 64; ++o)
                    acc[o] = fmaf(xs, wr[j * 64 + o], acc[o]);
            }
        }
    }
    float* op = out + (size_t)n * 64;
#pragma unroll
    for (int o = 0; o < 64; o += 4) {
        float4 v = {acc[o], acc[o + 1], acc[o + 2], acc[o + 3]};
        *(float4*)(op + o) = v;
    }
}

// ---------------------------------------------------------------------------
// In-place BN (train) + SiLU over h [N,64]. stats: [128] = sums, sumsqs.
// ---------------------------------------------------------------------------
__global__ __launch_bounds__(256) void bnsilu_k(float* __restrict__ h,
                                                const float* __restrict__ stats,
                                                const float* __restrict__ gamma,
                                                const float* __restrict__ beta,
                                                int total, float invN) {
    int i = blockIdx.x * 256 + threadIdx.x;
    if (i >= total) return;
    int c     = i & 63;
    float m   = stats[c] * invN;
    float var = stats[64 + c] * invN - m * m;
    float x   = (h[i] - m) * rsqrtf(var + EPSF) * gamma[c] + beta[c];
    h[i]      = x / (1.f + expf(-x));
}

// ---------------------------------------------------------------------------
// Fused point kernel: trilinear interp gather + point-branch BN+SiLU+Linear,
// writes z1, scatter-adds into voxel sums + counts.
// ---------------------------------------------------------------------------
__global__ __launch_bounds__(256) void point_k(
    const float* __restrict__ x,        // [N,64] conv2 out
    const float* __restrict__ z_feats,  // [P,32]
    const float* __restrict__ interp_w, // [P,8]
    const int* __restrict__ interp_idx, // [P,8]
    const int* __restrict__ p2v,        // [P]
    const float* __restrict__ lin_w,    // [32,64]
    const float* __restrict__ lin_b,    // [64]
    const float* __restrict__ pstats,   // [64] = sums(32), sumsqs(32)
    const float* __restrict__ pgamma,
    const float* __restrict__ pbeta,
    float* __restrict__ z1_out,         // [P,64]
    float* __restrict__ sums,           // [N,64] pre-zeroed
    float* __restrict__ cnt,            // [N]   pre-zeroed
    int P, float invP) {
    int p = blockIdx.x * 256 + threadIdx.x;
    if (p >= P) return;
    float acc[64];
#pragma unroll
    for (int o = 0; o < 64; ++o) acc[o] = 0.f;

    const int* ii   = interp_idx + (size_t)p * 8;
    const float* iw = interp_w + (size_t)p * 8;
    for (int t = 0; t < 8; ++t) {
        int idx          = ii[t];
        float w          = iw[t];
        const float4* xr = (const float4*)(x + (size_t)idx * 64);
#pragma unroll
        for (int c = 0; c < 16; ++c) {
            float4 v = xr[c];
            acc[c * 4 + 0] = fmaf(w, v.x, acc[c * 4 + 0]);
            acc[c * 4 + 1] = fmaf(w, v.y, acc[c * 4 + 1]);
            acc[c * 4 + 2] = fmaf(w, v.z, acc[c * 4 + 2]);
            acc[c * 4 + 3] = fmaf(w, v.w, acc[c * 4 + 3]);
        }
    }

    const float* zr = z_feats + (size_t)p * 32;
#pragma unroll
    for (int i = 0; i < 32; ++i) {
        float m   = pstats[i] * invP;
        float var = pstats[32 + i] * invP - m * m;
        float zn  = (zr[i] - m) * rsqrtf(var + EPSF) * pgamma[i] + pbeta[i];
        float pz  = zn / (1.f + expf(-zn)); // SiLU
#pragma unroll
        for (int o = 0; o < 64; ++o)
            acc[o] = fmaf(pz, lin_w[i * 64 + o], acc[o]);
    }
#pragma unroll
    for (int o = 0; o < 64; ++o) acc[o] += lin_b[o];

    float* zo = z1_out + (size_t)p * 64;
#pragma unroll
    for (int o = 0; o < 64; o += 4) {
        float4 v = {acc[o], acc[o + 1], acc[o + 2], acc[o + 3]};
        *(float4*)(zo + o) = v;
    }

    int vx    = p2v[p];
    float* sp = sums + (size_t)vx * 64;
#pragma unroll
    for (int o = 0; o < 64; ++o) atomicAdd(sp + o, acc[o]);
    atomicAdd(cnt + vx, 1.f);
}

// x_new[i] = sums[i] / max(cnt[i/64], 1)
__global__ __launch_bounds__(256) void fin_k(float* __restrict__ xnew,
                                             const float* __restrict__ cnt,
                                             int total) {
    int i = blockIdx.x * 256 + threadIdx.x;
    if (i >= total) return;
    float c = cnt[i >> 6];
    xnew[i] = xnew[i] / fmaxf(c, 1.f);
}

extern "C" void kernel_launch(void* const* d_in, const int* in_sizes, int n_in,
                              void* d_out, int out_size, void* d_ws, size_t ws_size,
                              hipStream_t stream) {
    const float* x_feats   = (const float*)d_in[0];
    const float* z_feats   = (const float*)d_in[1];
    const float* interp_w  = (const float*)d_in[2];
    const int* nbr_idx     = (const int*)d_in[3];
    const int* interp_idx  = (const int*)d_in[4];
    const int* p2v_idx     = (const int*)d_in[5];
    const float* conv1_w   = (const float*)d_in[6];
    const float* conv2_w   = (const float*)d_in[7];
    const float* bn_gamma  = (const float*)d_in[8];
    const float* bn_beta   = (const float*)d_in[9];
    const float* pbn_gamma = (const float*)d_in[10];
    const float* pbn_beta  = (const float*)d_in[11];
    const float* lin_w     = (const float*)d_in[12];
    const float* lin_b     = (const float*)d_in[13];

    const int N = in_sizes[3] / KOFF;  // 100000
    const int P = in_sizes[5];         // 200000

    // Workspace layout (floats): h[N*64] | x[N*64] | cnt[N] | stats_h[128] | stats_p[64]
    float* h       = (float*)d_ws;
    float* x       = h + (size_t)N * 64;
    float* cnt     = x + (size_t)N * 64;
    float* stats_h = cnt + N;
    float* stats_p = stats_h + 128;

    float* xnew = (float*)d_out;             // output 0: [N,64]
    float* z1   = xnew + (size_t)N * 64;     // output 1: [P,64]

    // Zero accumulators (cnt + both stats buffers are contiguous) and sums.
    hipMemsetAsync(cnt, 0, (size_t)(N + 192) * sizeof(float), stream);
    hipMemsetAsync(xnew, 0, (size_t)N * 64 * sizeof(float), stream);

    // Point-branch BN stats (independent of voxel branch).
    stats_k<32><<<256, 256, 0, stream>>>(z_feats, P, stats_p);

    // conv1: x_feats -> h
    conv_k<32><<<(N + 255) / 256, 256, 0, stream>>>(x_feats, nbr_idx, conv1_w, h, N);

    // BN stats over h, then BN+SiLU in place.
    stats_k<64><<<256, 256, 0, stream>>>(h, N, stats_h);
    int totalH = N * 64;
    bnsilu_k<<<(totalH + 255) / 256, 256, 0, stream>>>(h, stats_h, bn_gamma, bn_beta,
                                                       totalH, 1.f / (float)N);

    // conv2: h -> x
    conv_k<64><<<(N + 255) / 256, 256, 0, stream>>>(h, nbr_idx, conv2_w, x, N);

    // Fused point branch + scatter.
    point_k<<<(P + 255) / 256, 256, 0, stream>>>(x, z_feats, interp_w, interp_idx,
                                                 p2v_idx, lin_w, lin_b, stats_p,
                                                 pbn_gamma, pbn_beta, z1, xnew, cnt,
                                                 P, 1.f / (float)P);

    // x_new = sums / max(cnt, 1)
    fin_k<<<(totalH + 255) / 256, 256, 0, stream>>>(xnew, cnt, totalH);

    (void)n_in; (void)out_size; (void)ws_size;
}

// Round 2
// 1658.126 us; speedup vs baseline: 1.0209x; 1.0209x over previous
//
#include <hip/hip_runtime.h>
#include <cstdint>

#define EPSF 1e-5f
constexpr int KOFF = 27;

// ---------------------------------------------------------------------------
// Per-channel sum / sumsq over rows (training-mode BN stats).
// v: [n, C] row-major. out: [2*C] (sums, then sumsqs). Must be pre-zeroed.
// ---------------------------------------------------------------------------
template <int C>
__global__ __launch_bounds__(256) void stats_k(const float* __restrict__ v, int n,
                                               float* __restrict__ out) {
    __shared__ float ls[2 * 256];
    const int c   = threadIdx.x % C;
    const int rpb = 256 / C;
    int r0     = blockIdx.x * rpb + threadIdx.x / C;
    int stride = gridDim.x * rpb;
    float s = 0.f, ss = 0.f;
    for (int r = r0; r < n; r += stride) {
        float x = v[(size_t)r * C + c];
        s += x;
        ss += x * x;
    }
    ls[threadIdx.x]       = s;
    ls[256 + threadIdx.x] = ss;
    __syncthreads();
    for (int off = 128; off >= C; off >>= 1) {
        if (threadIdx.x < off) {
            ls[threadIdx.x] += ls[threadIdx.x + off];
            ls[256 + threadIdx.x] += ls[256 + threadIdx.x + off];
        }
        __syncthreads();
    }
    if (threadIdx.x < C) {
        atomicAdd(&out[threadIdx.x], ls[threadIdx.x]);
        atomicAdd(&out[C + threadIdx.x], ls[256 + threadIdx.x]);
    }
}

// ---------------------------------------------------------------------------
// Gather conv, wave-split outputs: block = 256 threads = 4 waves over 64 rows.
// Wave w computes output channels [16w, 16w+16) for all 64 rows.
// Weight base is wave-uniform (readfirstlane) -> scalar loads -> FMA w/ SGPR.
// ---------------------------------------------------------------------------
template <int CIN>
__global__ __launch_bounds__(256) void conv_k(const float* __restrict__ feats,
                                              const int* __restrict__ nbr,
                                              const float* __restrict__ W,
                                              float* __restrict__ out, int N) {
    const int lane = threadIdx.x & 63;
    const int wv   = threadIdx.x >> 6;
    const int row  = blockIdx.x * 64 + lane;
    if (row >= N) return;
    const int wbase = __builtin_amdgcn_readfirstlane(wv * 16);

    float acc[16];
#pragma unroll
    for (int o = 0; o < 16; ++o) acc[o] = 0.f;

    const int* nb = nbr + (size_t)row * KOFF;
    for (int k = 0; k < KOFF; ++k) {
        int idx          = nb[k];
        const float4* xr = (const float4*)(feats + (size_t)idx * CIN);
        const float* wk  = W + (size_t)k * CIN * 64 + wbase;
#pragma unroll
        for (int i4 = 0; i4 < CIN / 4; ++i4) {
            float4 xv = xr[i4];
#pragma unroll
            for (int j = 0; j < 4; ++j) {
                float xs        = (&xv.x)[j];
                const float* wr = wk + (i4 * 4 + j) * 64;
#pragma unroll
                for (int o = 0; o < 16; ++o)
                    acc[o] = fmaf(xs, wr[o], acc[o]);
            }
        }
    }
    float* op = out + (size_t)row * 64 + wbase;
#pragma unroll
    for (int o = 0; o < 16; o += 4) {
        float4 v = {acc[o], acc[o + 1], acc[o + 2], acc[o + 3]};
        *(float4*)(op + o) = v;
    }
}

// ---------------------------------------------------------------------------
// In-place BN (train) + SiLU over h [N,64], float4-vectorized.
// ---------------------------------------------------------------------------
__global__ __launch_bounds__(256) void bnsilu_k(float* __restrict__ h,
                                                const float* __restrict__ stats,
                                                const float* __restrict__ gamma,
                                                const float* __restrict__ beta,
                                                int total4, float invN) {
    int i4 = blockIdx.x * 256 + threadIdx.x;
    if (i4 >= total4) return;
    int c0    = (i4 * 4) & 63;
    float4 v  = ((const float4*)h)[i4];
#pragma unroll
    for (int j = 0; j < 4; ++j) {
        int c     = c0 + j;
        float m   = stats[c] * invN;
        float var = stats[64 + c] * invN - m * m;
        float x   = ((&v.x)[j] - m) * rsqrtf(var + EPSF) * gamma[c] + beta[c];
        (&v.x)[j] = x / (1.f + expf(-x));
    }
    ((float4*)h)[i4] = v;
}

// ---------------------------------------------------------------------------
// Fused point kernel, wave-split channels: block = 4 waves over 64 points,
// wave w handles channels [16w, 16w+16).
// ---------------------------------------------------------------------------
__global__ __launch_bounds__(256) void point_k(
    const float* __restrict__ x,        // [N,64] conv2 out
    const float* __restrict__ z_feats,  // [P,32]
    const float* __restrict__ interp_w, // [P,8]
    const int* __restrict__ interp_idx, // [P,8]
    const int* __restrict__ p2v,        // [P]
    const float* __restrict__ lin_w,    // [32,64]
    const float* __restrict__ lin_b,    // [64]
    const float* __restrict__ pstats,   // [64] = sums(32), sumsqs(32)
    const float* __restrict__ pgamma,
    const float* __restrict__ pbeta,
    float* __restrict__ z1_out,         // [P,64]
    float* __restrict__ sums,           // [N,64] pre-zeroed
    float* __restrict__ cnt,            // [N]   pre-zeroed
    int P, float invP) {
    const int lane = threadIdx.x & 63;
    const int wv   = threadIdx.x >> 6;
    const int p    = blockIdx.x * 64 + lane;
    if (p >= P) return;
    const int wbase = __builtin_amdgcn_readfirstlane(wv * 16);

    // Interp metadata (vector loads).
    const int4* iip   = (const int4*)(interp_idx + (size_t)p * 8);
    const float4* iwp = (const float4*)(interp_w + (size_t)p * 8);
    int4 ia = iip[0], ib = iip[1];
    float4 wa = iwp[0], wb = iwp[1];
    int idxs[8]  = {ia.x, ia.y, ia.z, ia.w, ib.x, ib.y, ib.z, ib.w};
    float wts[8] = {wa.x, wa.y, wa.z, wa.w, wb.x, wb.y, wb.z, wb.w};

    float acc[16];
#pragma unroll
    for (int o = 0; o < 16; ++o) acc[o] = 0.f;

#pragma unroll
    for (int t = 0; t < 8; ++t) {
        const float4* xr = (const float4*)(x + (size_t)idxs[t] * 64 + wbase);
        float w          = wts[t];
#pragma unroll
        for (int c = 0; c < 4; ++c) {
            float4 v = xr[c];
            acc[c * 4 + 0] = fmaf(w, v.x, acc[c * 4 + 0]);
            acc[c * 4 + 1] = fmaf(w, v.y, acc[c * 4 + 1]);
            acc[c * 4 + 2] = fmaf(w, v.z, acc[c * 4 + 2]);
            acc[c * 4 + 3] = fmaf(w, v.w, acc[c * 4 + 3]);
        }
    }

    // Point branch: BN+SiLU(z) @ lin_w slice, interleaved to keep VGPRs low.
    const float4* zr4 = (const float4*)(z_feats + (size_t)p * 32);
#pragma unroll
    for (int i4 = 0; i4 < 8; ++i4) {
        float4 zv = zr4[i4];
#pragma unroll
        for (int j = 0; j < 4; ++j) {
            int i     = i4 * 4 + j;
            float m   = pstats[i] * invP;
            float var = pstats[32 + i] * invP - m * m;
            float zn  = ((&zv.x)[j] - m) * rsqrtf(var + EPSF) * pgamma[i] + pbeta[i];
            float pz  = zn / (1.f + expf(-zn));
            const float* lw = lin_w + i * 64 + wbase;
#pragma unroll
            for (int o = 0; o < 16; ++o)
                acc[o] = fmaf(pz, lw[o], acc[o]);
        }
    }
    const float* lb = lin_b + wbase;
#pragma unroll
    for (int o = 0; o < 16; ++o) acc[o] += lb[o];

    float* zo = z1_out + (size_t)p * 64 + wbase;
#pragma unroll
    for (int o = 0; o < 16; o += 4) {
        float4 v = {acc[o], acc[o + 1], acc[o + 2], acc[o + 3]};
        *(float4*)(zo + o) = v;
    }

    int vx    = p2v[p];
    float* sp = sums + (size_t)vx * 64 + wbase;
#pragma unroll
    for (int o = 0; o < 16; ++o) atomicAdd(sp + o, acc[o]);
    if (wv == 0) atomicAdd(cnt + vx, 1.f);
}

// x_new[i] = sums[i] / max(cnt[i/64], 1), float4-vectorized
__global__ __launch_bounds__(256) void fin_k(float* __restrict__ xnew,
                                             const float* __restrict__ cnt,
                                             int total4) {
    int i4 = blockIdx.x * 256 + threadIdx.x;
    if (i4 >= total4) return;
    float c  = cnt[i4 >> 4];
    float rc = 1.f / fmaxf(c, 1.f);
    float4 v = ((const float4*)xnew)[i4];
    v.x *= rc; v.y *= rc; v.z *= rc; v.w *= rc;
    ((float4*)xnew)[i4] = v;
}

extern "C" void kernel_launch(void* const* d_in, const int* in_sizes, int n_in,
                              void* d_out, int out_size, void* d_ws, size_t ws_size,
                              hipStream_t stream) {
    const float* x_feats   = (const float*)d_in[0];
    const float* z_feats   = (const float*)d_in[1];
    const float* interp_w  = (const float*)d_in[2];
    const int* nbr_idx     = (const int*)d_in[3];
    const int* interp_idx  = (const int*)d_in[4];
    const int* p2v_idx     = (const int*)d_in[5];
    const float* conv1_w   = (const float*)d_in[6];
    const float* conv2_w   = (const float*)d_in[7];
    const float* bn_gamma  = (const float*)d_in[8];
    const float* bn_beta   = (const float*)d_in[9];
    const float* pbn_gamma = (const float*)d_in[10];
    const float* pbn_beta  = (const float*)d_in[11];
    const float* lin_w     = (const float*)d_in[12];
    const float* lin_b     = (const float*)d_in[13];

    const int N = in_sizes[3] / KOFF;  // 100000
    const int P = in_sizes[5];         // 200000

    // Workspace layout (floats): h[N*64] | x[N*64] | cnt[N] | stats_h[128] | stats_p[64]
    float* h       = (float*)d_ws;
    float* x       = h + (size_t)N * 64;
    float* cnt     = x + (size_t)N * 64;
    float* stats_h = cnt + N;
    float* stats_p = stats_h + 128;

    float* xnew = (float*)d_out;             // output 0: [N,64]
    float* z1   = xnew + (size_t)N * 64;     // output 1: [P,64]

    hipMemsetAsync(cnt, 0, (size_t)(N + 192) * sizeof(float), stream);
    hipMemsetAsync(xnew, 0, (size_t)N * 64 * sizeof(float), stream);

    // Point-branch BN stats (independent of voxel branch).
    stats_k<32><<<256, 256, 0, stream>>>(z_feats, P, stats_p);

    // conv1: x_feats -> h
    conv_k<32><<<(N + 63) / 64, 256, 0, stream>>>(x_feats, nbr_idx, conv1_w, h, N);

    // BN stats over h, then BN+SiLU in place.
    stats_k<64><<<256, 256, 0, stream>>>(h, N, stats_h);
    int totalH = N * 64;
    bnsilu_k<<<(totalH / 4 + 255) / 256, 256, 0, stream>>>(h, stats_h, bn_gamma,
                                                           bn_beta, totalH / 4,
                                                           1.f / (float)N);

    // conv2: h -> x
    conv_k<64><<<(N + 63) / 64, 256, 0, stream>>>(h, nbr_idx, conv2_w, x, N);

    // Fused point branch + scatter.
    point_k<<<(P + 63) / 64, 256, 0, stream>>>(x, z_feats, interp_w, interp_idx,
                                               p2v_idx, lin_w, lin_b, stats_p,
                                               pbn_gamma, pbn_beta, z1, xnew, cnt,
                                               P, 1.f / (float)P);

    // x_new = sums / max(cnt, 1)
    fin_k<<<(totalH / 4 + 255) / 256, 256, 0, stream>>>(xnew, cnt, totalH / 4);

    (void)n_in; (void)out_size; (void)ws_size;
}

// Round 3
// 742.100 us; speedup vs baseline: 2.2811x; 2.2344x over previous
//
#include <hip/hip_runtime.h>
#include <cstdint>

#define EPSF 1e-5f
constexpr int KOFF = 27;

__device__ __forceinline__ void gload_lds16(const float* g, float* l) {
    __builtin_amdgcn_global_load_lds(
        (const __attribute__((address_space(1))) void*)g,
        (__attribute__((address_space(3))) void*)l, 16, 0, 0);
}

// ---------------------------------------------------------------------------
// Per-channel sum / sumsq over rows. out [2*C] pre-zeroed.
// ---------------------------------------------------------------------------
template <int C>
__global__ __launch_bounds__(256) void stats_k(const float* __restrict__ v, int n,
                                               float* __restrict__ out) {
    __shared__ float ls[2 * 256];
    const int c   = threadIdx.x % C;
    const int rpb = 256 / C;
    int r0     = blockIdx.x * rpb + threadIdx.x / C;
    int stride = gridDim.x * rpb;
    float s = 0.f, ss = 0.f;
    for (int r = r0; r < n; r += stride) {
        float x = v[(size_t)r * C + c];
        s += x;
        ss += x * x;
    }
    ls[threadIdx.x]       = s;
    ls[256 + threadIdx.x] = ss;
    __syncthreads();
    for (int off = 128; off >= C; off >>= 1) {
        if (threadIdx.x < off) {
            ls[threadIdx.x] += ls[threadIdx.x + off];
            ls[256 + threadIdx.x] += ls[256 + threadIdx.x + off];
        }
        __syncthreads();
    }
    if (threadIdx.x < C) {
        atomicAdd(&out[threadIdx.x], ls[threadIdx.x]);
        atomicAdd(&out[C + threadIdx.x], ls[256 + threadIdx.x]);
    }
}

// ---------------------------------------------------------------------------
// LDS-staged gather conv. Block = 64 rows x 4 waves; wave w computes output
// channels [16w,16w+16). Per k-offset the 64 gathered rows are staged in LDS
// (seg-major: chunk c = s*64 + r at byte c*16), double-buffered via
// global_load_lds (linear dest: wave-uniform base + lane*16).
// ---------------------------------------------------------------------------
template <int CIN>
__global__ __launch_bounds__(256) void conv_k(const float* __restrict__ feats,
                                              const int* __restrict__ nbr,
                                              const float* __restrict__ W,
                                              float* __restrict__ out, int N) {
    constexpr int SEGS = CIN / 4;              // 16B chunks per row
    __shared__ float lds[2][SEGS * 64 * 4];
    const int lane = threadIdx.x & 63;
    const int wv   = threadIdx.x >> 6;
    const int row  = blockIdx.x * 64 + lane;
    const bool valid = row < N;
    const int rowc   = valid ? row : N - 1;
    const int* nb    = nbr + (size_t)rowc * KOFF;
    const int wbase  = __builtin_amdgcn_readfirstlane(wv * 16);

    float acc[16];
#pragma unroll
    for (int o = 0; o < 16; ++o) acc[o] = 0.f;

    // stage rows for offset k into buffer b: thread stages segs s = i*4+wv of
    // its own row (row = lane); chunk c = s*64+lane -> uniform base + lane*16.
    auto stage = [&](int k, int b) {
        int idx          = nb[k];
        const float* src = feats + (size_t)idx * CIN;
#pragma unroll
        for (int i = 0; i < SEGS / 4; ++i) {
            int s      = i * 4 + wv;
            float* dst = &lds[b][(i * 256 + wv * 64) * 4];
            gload_lds16(src + s * 4, dst);
        }
    };

    auto compute = [&](int k, int b) {
        const float* wk = W + (size_t)k * CIN * 64 + wbase;
#pragma unroll
        for (int s = 0; s < SEGS; ++s) {
            float4 xv = *(const float4*)&lds[b][(s * 64 + lane) * 4];
#pragma unroll
            for (int j = 0; j < 4; ++j) {
                float xs        = (&xv.x)[j];
                const float* wr = wk + (s * 4 + j) * 64;
#pragma unroll
                for (int o = 0; o < 16; ++o)
                    acc[o] = fmaf(xs, wr[o], acc[o]);
            }
        }
    };

    stage(0, 0);
    __syncthreads();
    for (int k = 0; k < KOFF; ++k) {
        int b = k & 1;
        if (k + 1 < KOFF) stage(k + 1, b ^ 1);   // async, lands before barrier
        compute(k, b);
        __syncthreads();
    }

    if (valid) {
        float* op = out + (size_t)row * 64 + wbase;
#pragma unroll
        for (int o = 0; o < 16; o += 4) {
            float4 v = {acc[o], acc[o + 1], acc[o + 2], acc[o + 3]};
            *(float4*)(op + o) = v;
        }
    }
}

// ---------------------------------------------------------------------------
// In-place BN (train) + SiLU over h [N,64], float4-vectorized.
// ---------------------------------------------------------------------------
__global__ __launch_bounds__(256) void bnsilu_k(float* __restrict__ h,
                                                const float* __restrict__ stats,
                                                const float* __restrict__ gamma,
                                                const float* __restrict__ beta,
                                                int total4, float invN) {
    int i4 = blockIdx.x * 256 + threadIdx.x;
    if (i4 >= total4) return;
    int c0    = (i4 * 4) & 63;
    float4 v  = ((const float4*)h)[i4];
#pragma unroll
    for (int j = 0; j < 4; ++j) {
        int c     = c0 + j;
        float m   = stats[c] * invN;
        float var = stats[64 + c] * invN - m * m;
        float x   = ((&v.x)[j] - m) * rsqrtf(var + EPSF) * gamma[c] + beta[c];
        (&v.x)[j] = x / (1.f + expf(-x));
    }
    ((float4*)h)[i4] = v;
}

// ---------------------------------------------------------------------------
// Point branch: trilinear gather + BN+SiLU+Linear -> z1. NO scatter.
// Block = 4 waves over 64 points; wave w owns channels [16w,16w+16).
// ---------------------------------------------------------------------------
__global__ __launch_bounds__(256) void point_k(
    const float* __restrict__ x, const float* __restrict__ z_feats,
    const float* __restrict__ interp_w, const int* __restrict__ interp_idx,
    const float* __restrict__ lin_w, const float* __restrict__ lin_b,
    const float* __restrict__ pstats, const float* __restrict__ pgamma,
    const float* __restrict__ pbeta, float* __restrict__ z1_out,
    int P, float invP) {
    const int lane = threadIdx.x & 63;
    const int wv   = threadIdx.x >> 6;
    const int p    = blockIdx.x * 64 + lane;
    if (p >= P) return;
    const int wbase = __builtin_amdgcn_readfirstlane(wv * 16);

    const int4* iip   = (const int4*)(interp_idx + (size_t)p * 8);
    const float4* iwp = (const float4*)(interp_w + (size_t)p * 8);
    int4 ia = iip[0], ib = iip[1];
    float4 wa = iwp[0], wb = iwp[1];
    int idxs[8]  = {ia.x, ia.y, ia.z, ia.w, ib.x, ib.y, ib.z, ib.w};
    float wts[8] = {wa.x, wa.y, wa.z, wa.w, wb.x, wb.y, wb.z, wb.w};

    float acc[16];
#pragma unroll
    for (int o = 0; o < 16; ++o) acc[o] = 0.f;

#pragma unroll
    for (int t = 0; t < 8; ++t) {
        const float4* xr = (const float4*)(x + (size_t)idxs[t] * 64 + wbase);
        float w          = wts[t];
#pragma unroll
        for (int c = 0; c < 4; ++c) {
            float4 v = xr[c];
            acc[c * 4 + 0] = fmaf(w, v.x, acc[c * 4 + 0]);
            acc[c * 4 + 1] = fmaf(w, v.y, acc[c * 4 + 1]);
            acc[c * 4 + 2] = fmaf(w, v.z, acc[c * 4 + 2]);
            acc[c * 4 + 3] = fmaf(w, v.w, acc[c * 4 + 3]);
        }
    }

    const float4* zr4 = (const float4*)(z_feats + (size_t)p * 32);
#pragma unroll
    for (int i4 = 0; i4 < 8; ++i4) {
        float4 zv = zr4[i4];
#pragma unroll
        for (int j = 0; j < 4; ++j) {
            int i     = i4 * 4 + j;
            float m   = pstats[i] * invP;
            float var = pstats[32 + i] * invP - m * m;
            float zn  = ((&zv.x)[j] - m) * rsqrtf(var + EPSF) * pgamma[i] + pbeta[i];
            float pz  = zn / (1.f + expf(-zn));
            const float* lw = lin_w + i * 64 + wbase;
#pragma unroll
            for (int o = 0; o < 16; ++o)
                acc[o] = fmaf(pz, lw[o], acc[o]);
        }
    }
    const float* lb = lin_b + wbase;
#pragma unroll
    for (int o = 0; o < 16; ++o) acc[o] += lb[o];

    float* zo = z1_out + (size_t)p * 64 + wbase;
#pragma unroll
    for (int o = 0; o < 16; o += 4) {
        float4 v = {acc[o], acc[o + 1], acc[o + 2], acc[o + 3]};
        *(float4*)(zo + o) = v;
    }
}

// --------------------------- CSR build + gather-average ---------------------
__global__ __launch_bounds__(256) void hist_k(const int* __restrict__ p2v,
                                              int* __restrict__ cnt, int P) {
    int p = blockIdx.x * 256 + threadIdx.x;
    if (p < P) atomicAdd(&cnt[p2v[p]], 1);
}

// per-block inclusive scan of cnt -> tmp, block totals -> bsum
__global__ __launch_bounds__(256) void scan1_k(const int* __restrict__ cnt,
                                               int* __restrict__ tmp,
                                               int* __restrict__ bsum, int n) {
    __shared__ int s[256];
    int i = blockIdx.x * 256 + threadIdx.x;
    int v = (i < n) ? cnt[i] : 0;
    s[threadIdx.x] = v;
    __syncthreads();
    for (int off = 1; off < 256; off <<= 1) {
        int t = (threadIdx.x >= off) ? s[threadIdx.x - off] : 0;
        __syncthreads();
        s[threadIdx.x] += t;
        __syncthreads();
    }
    if (i < n) tmp[i] = s[threadIdx.x];
    if (threadIdx.x == 255) bsum[blockIdx.x] = s[255];
}

__global__ void scan2_k(const int* __restrict__ bsum, int* __restrict__ bpre,
                        int nb) {
    if (blockIdx.x == 0 && threadIdx.x == 0) {
        int a = 0;
        for (int b = 0; b < nb; ++b) { bpre[b] = a; a += bsum[b]; }
    }
}

// off[i] = exclusive scan = bpre[blk] + tmp[i] - cnt[i]
__global__ __launch_bounds__(256) void scan3_k(const int* __restrict__ cnt,
                                               const int* __restrict__ tmp,
                                               const int* __restrict__ bpre,
                                               int* __restrict__ off, int n) {
    int i = blockIdx.x * 256 + threadIdx.x;
    if (i < n) off[i] = bpre[i >> 8] + tmp[i] - cnt[i];
}

__global__ __launch_bounds__(256) void fill_k(const int* __restrict__ p2v,
                                              const int* __restrict__ off,
                                              int* __restrict__ cursor,
                                              int* __restrict__ bucket, int P) {
    int p = blockIdx.x * 256 + threadIdx.x;
    if (p >= P) return;
    int v    = p2v[p];
    int slot = atomicAdd(&cursor[v], 1);
    bucket[off[v] + slot] = p;
}

// x_new[v] = mean of z1 rows of points in voxel v (gather, no atomics).
// Thread = (voxel, 16-channel quarter).
__global__ __launch_bounds__(256) void avg_k(const float* __restrict__ z1,
                                             const int* __restrict__ off,
                                             const int* __restrict__ cnt,
                                             const int* __restrict__ bucket,
                                             float* __restrict__ xnew, int N) {
    int tid = blockIdx.x * 256 + threadIdx.x;
    int v   = tid >> 2;
    if (v >= N) return;
    int q  = tid & 3;
    int c  = cnt[v];
    int st = off[v];
    float acc[16];
#pragma unroll
    for (int o = 0; o < 16; ++o) acc[o] = 0.f;
    for (int j = 0; j < c; ++j) {
        int p            = bucket[st + j];
        const float4* zr = (const float4*)(z1 + (size_t)p * 64 + q * 16);
#pragma unroll
        for (int c4 = 0; c4 < 4; ++c4) {
            float4 t = zr[c4];
            acc[c4 * 4 + 0] += t.x;
            acc[c4 * 4 + 1] += t.y;
            acc[c4 * 4 + 2] += t.z;
            acc[c4 * 4 + 3] += t.w;
        }
    }
    float rc  = 1.f / fmaxf((float)c, 1.f);
    float* op = xnew + (size_t)v * 64 + q * 16;
#pragma unroll
    for (int o = 0; o < 16; o += 4) {
        float4 t = {acc[o] * rc, acc[o + 1] * rc, acc[o + 2] * rc, acc[o + 3] * rc};
        *(float4*)(op + o) = t;
    }
}

extern "C" void kernel_launch(void* const* d_in, const int* in_sizes, int n_in,
                              void* d_out, int out_size, void* d_ws, size_t ws_size,
                              hipStream_t stream) {
    const float* x_feats   = (const float*)d_in[0];
    const float* z_feats   = (const float*)d_in[1];
    const float* interp_w  = (const float*)d_in[2];
    const int* nbr_idx     = (const int*)d_in[3];
    const int* interp_idx  = (const int*)d_in[4];
    const int* p2v_idx     = (const int*)d_in[5];
    const float* conv1_w   = (const float*)d_in[6];
    const float* conv2_w   = (const float*)d_in[7];
    const float* bn_gamma  = (const float*)d_in[8];
    const float* bn_beta   = (const float*)d_in[9];
    const float* pbn_gamma = (const float*)d_in[10];
    const float* pbn_beta  = (const float*)d_in[11];
    const float* lin_w     = (const float*)d_in[12];
    const float* lin_b     = (const float*)d_in[13];

    const int N  = in_sizes[3] / KOFF;  // 100000
    const int P  = in_sizes[5];         // 200000
    const int NB = (N + 255) / 256;     // scan blocks

    // Workspace layout
    float* h      = (float*)d_ws;                  // [N*64]
    float* x      = h + (size_t)N * 64;            // [N*64]
    int* cnt      = (int*)(x + (size_t)N * 64);    // [N]
    int* cursor   = cnt + N;                       // [N]
    float* stats  = (float*)(cursor + N);          // [192]: stats_h 128 | stats_p 64
    int* tmp      = (int*)(stats + 192);           // [N]
    int* off      = tmp + N;                       // [N]
    int* bsum     = off + N;                       // [512]
    int* bpre     = bsum + 512;                    // [512]
    int* bucket   = bpre + 512;                    // [P]
    float* stats_h = stats;
    float* stats_p = stats + 128;

    float* xnew = (float*)d_out;             // [N,64]
    float* z1   = xnew + (size_t)N * 64;     // [P,64]

    // Zero cnt, cursor, stats (contiguous).
    hipMemsetAsync(cnt, 0, ((size_t)2 * N + 192) * sizeof(float), stream);

    // CSR build (independent of features).
    hist_k<<<(P + 255) / 256, 256, 0, stream>>>(p2v_idx, cnt, P);
    scan1_k<<<NB, 256, 0, stream>>>(cnt, tmp, bsum, N);
    scan2_k<<<1, 1, 0, stream>>>(bsum, bpre, NB);
    scan3_k<<<NB, 256, 0, stream>>>(cnt, tmp, bpre, off, N);
    fill_k<<<(P + 255) / 256, 256, 0, stream>>>(p2v_idx, off, cursor, bucket, P);

    // Point-branch BN stats.
    stats_k<32><<<256, 256, 0, stream>>>(z_feats, P, stats_p);

    // conv1: x_feats -> h
    conv_k<32><<<(N + 63) / 64, 256, 0, stream>>>(x_feats, nbr_idx, conv1_w, h, N);

    // BN stats + BN+SiLU in place.
    stats_k<64><<<256, 256, 0, stream>>>(h, N, stats_h);
    int totalH = N * 64;
    bnsilu_k<<<(totalH / 4 + 255) / 256, 256, 0, stream>>>(h, stats_h, bn_gamma,
                                                           bn_beta, totalH / 4,
                                                           1.f / (float)N);

    // conv2: h -> x
    conv_k<64><<<(N + 63) / 64, 256, 0, stream>>>(h, nbr_idx, conv2_w, x, N);

    // Point branch -> z1 (no scatter).
    point_k<<<(P + 63) / 64, 256, 0, stream>>>(x, z_feats, interp_w, interp_idx,
                                               lin_w, lin_b, stats_p, pbn_gamma,
                                               pbn_beta, z1, P, 1.f / (float)P);

    // Gather-average into x_new.
    avg_k<<<((size_t)N * 4 + 255) / 256, 256, 0, stream>>>(z1, off, cnt, bucket,
                                                           xnew, N);

    (void)n_in; (void)out_size; (void)ws_size;
}

// Round 4
// 566.793 us; speedup vs baseline: 2.9866x; 1.3093x over previous
//
#include <hip/hip_runtime.h>
#include <cstdint>

#define EPSF 1e-5f
constexpr int KOFF = 27;

typedef __attribute__((ext_vector_type(8))) short bf16x8;
typedef __attribute__((ext_vector_type(4))) float f32x4;
typedef unsigned short ushort_t;
typedef unsigned int uint_t;

// bf16 (bits) -> f32
__device__ __forceinline__ float b2f(ushort_t u) {
    return __uint_as_float(((uint_t)u) << 16);
}
// f32 -> bf16 bits, RNE
__device__ __forceinline__ ushort_t f2b(float f) {
    uint_t u = __float_as_uint(f);
    u += 0x7fffu + ((u >> 16) & 1u);
    return (ushort_t)(u >> 16);
}
// uint4 (8 packed bf16) -> 8 floats
__device__ __forceinline__ void u4tof(uint4 u, float* f) {
    uint_t w[4] = {u.x, u.y, u.z, u.w};
#pragma unroll
    for (int i = 0; i < 4; ++i) {
        f[2 * i]     = __uint_as_float(w[i] << 16);
        f[2 * i + 1] = __uint_as_float(w[i] & 0xffff0000u);
    }
}

// ---------------------------------------------------------------------------
// f32 -> bf16 convert, 8 elems/thread.
// ---------------------------------------------------------------------------
__global__ __launch_bounds__(256) void cvt_k(const float* __restrict__ in,
                                             ushort_t* __restrict__ out, int n8) {
    int i = blockIdx.x * 256 + threadIdx.x;
    if (i >= n8) return;
    float4 a = ((const float4*)in)[2 * i];
    float4 b = ((const float4*)in)[2 * i + 1];
    uint4 o;
    o.x = (uint_t)f2b(a.x) | ((uint_t)f2b(a.y) << 16);
    o.y = (uint_t)f2b(a.z) | ((uint_t)f2b(a.w) << 16);
    o.z = (uint_t)f2b(b.x) | ((uint_t)f2b(b.y) << 16);
    o.w = (uint_t)f2b(b.z) | ((uint_t)f2b(b.w) << 16);
    ((uint4*)out)[i] = o;
}

// W [27][CIN][64] f32 -> Wt [27][64][CIN] bf16
__global__ __launch_bounds__(256) void wtT_k(const float* __restrict__ W,
                                             ushort_t* __restrict__ Wt, int CIN) {
    int t     = blockIdx.x * 256 + threadIdx.x;
    int total = KOFF * CIN * 64;
    if (t >= total) return;
    int o    = t & 63;
    int rest = t >> 6;
    int i    = rest % CIN;
    int k    = rest / CIN;
    Wt[((size_t)k * 64 + o) * CIN + i] = f2b(W[t]);
}

// ---------------------------------------------------------------------------
// MFMA gather conv. Block = 256 thr = 4 waves; wave q owns rows
// [blk*64+16q, +16), all 64 output cols. A-frags loaded per-lane direct from
// global (16B each); B-frags from transposed bf16 weights (L1-hot).
// Depth-3 software pipeline on the A gathers.
// ---------------------------------------------------------------------------
template <int CIN, bool OUT_BF16>
__global__ __launch_bounds__(256, 4) void convm_k(
    const ushort_t* __restrict__ feats,  // [N][CIN] bf16
    const int* __restrict__ nbr,         // [N][27]
    const ushort_t* __restrict__ Wt,     // [27][64][CIN] bf16
    void* __restrict__ outp,             // [N][64] (f32 or bf16)
    int N) {
    constexpr int T = CIN / 32;  // K-steps per neighbor
    const int lane = threadIdx.x & 63;
    const int lo   = lane & 15;
    const int hi   = lane >> 4;
    const int row0 = blockIdx.x * 64 + (threadIdx.x >> 6) * 16;
    const int mrow = row0 + lo;
    const int mrowc = mrow < N ? mrow : N - 1;
    const int* nb   = nbr + (size_t)mrowc * KOFF;

    f32x4 acc[4] = {{0.f, 0.f, 0.f, 0.f},
                    {0.f, 0.f, 0.f, 0.f},
                    {0.f, 0.f, 0.f, 0.f},
                    {0.f, 0.f, 0.f, 0.f}};

    bf16x8 a0[T], a1[T], a2[T];

    auto LOADA = [&](bf16x8 (&buf)[T], int k) {
        int idx            = nb[k];
        const ushort_t* s  = feats + (size_t)idx * CIN + hi * 8;
#pragma unroll
        for (int t = 0; t < T; ++t) buf[t] = *(const bf16x8*)(s + t * 32);
    };
    auto PROC = [&](bf16x8 (&A)[T], int k) {
        const ushort_t* wb = Wt + ((size_t)k * 64 + lo) * CIN + hi * 8;
#pragma unroll
        for (int nt = 0; nt < 4; ++nt) {
#pragma unroll
            for (int t = 0; t < T; ++t) {
                bf16x8 b = *(const bf16x8*)(wb + (size_t)nt * 16 * CIN + t * 32);
                acc[nt]  = __builtin_amdgcn_mfma_f32_16x16x32_bf16(A[t], b, acc[nt],
                                                                   0, 0, 0);
            }
        }
    };

    LOADA(a0, 0);
    LOADA(a1, 1);
    LOADA(a2, 2);
    for (int k = 0; k < KOFF; k += 3) {
        PROC(a0, k);
        if (k + 3 < KOFF) LOADA(a0, k + 3);
        PROC(a1, k + 1);
        if (k + 4 < KOFF) LOADA(a1, k + 4);
        PROC(a2, k + 2);
        if (k + 5 < KOFF) LOADA(a2, k + 5);
    }

    // C/D layout: col = lane&15, row = (lane>>4)*4 + reg.
#pragma unroll
    for (int r = 0; r < 4; ++r) {
        int orow = row0 + hi * 4 + r;
        if (orow < N) {
#pragma unroll
            for (int nt = 0; nt < 4; ++nt) {
                float v = acc[nt][r];
                if (OUT_BF16)
                    ((ushort_t*)outp)[(size_t)orow * 64 + nt * 16 + lo] = f2b(v);
                else
                    ((float*)outp)[(size_t)orow * 64 + nt * 16 + lo] = v;
            }
        }
    }
}

// ---------------------------------------------------------------------------
// Per-channel sum/sumsq over f32 [n,C]. out [2C] pre-zeroed.
// ---------------------------------------------------------------------------
template <int C>
__global__ __launch_bounds__(256) void stats_k(const float* __restrict__ v, int n,
                                               float* __restrict__ out) {
    __shared__ float ls[2 * 256];
    const int c   = threadIdx.x % C;
    const int rpb = 256 / C;
    int r0     = blockIdx.x * rpb + threadIdx.x / C;
    int stride = gridDim.x * rpb;
    float s = 0.f, ss = 0.f;
    for (int r = r0; r < n; r += stride) {
        float x = v[(size_t)r * C + c];
        s += x;
        ss += x * x;
    }
    ls[threadIdx.x]       = s;
    ls[256 + threadIdx.x] = ss;
    __syncthreads();
    for (int off = 128; off >= C; off >>= 1) {
        if (threadIdx.x < off) {
            ls[threadIdx.x] += ls[threadIdx.x + off];
            ls[256 + threadIdx.x] += ls[256 + threadIdx.x + off];
        }
        __syncthreads();
    }
    if (threadIdx.x < C) {
        atomicAdd(&out[threadIdx.x], ls[threadIdx.x]);
        atomicAdd(&out[C + threadIdx.x], ls[256 + threadIdx.x]);
    }
}

// Per-channel sum/sumsq over bf16 [n,64], vectorized (8 ch/thread).
__global__ __launch_bounds__(256) void statsb_k(const ushort_t* __restrict__ v,
                                                int n, float* __restrict__ out) {
    __shared__ float ls[2][256];
    const int c8 = threadIdx.x & 7;    // channel block [c8*8, +8)
    int r0 = blockIdx.x * 32 + (threadIdx.x >> 3);
    float s[8], ss[8];
#pragma unroll
    for (int j = 0; j < 8; ++j) { s[j] = 0.f; ss[j] = 0.f; }
    for (int r = r0; r < n; r += gridDim.x * 32) {
        uint4 u = *(const uint4*)(v + (size_t)r * 64 + c8 * 8);
        float f[8];
        u4tof(u, f);
#pragma unroll
        for (int j = 0; j < 8; ++j) { s[j] += f[j]; ss[j] += f[j] * f[j]; }
    }
#pragma unroll
    for (int j = 0; j < 8; ++j) {
        ls[0][threadIdx.x] = s[j];
        ls[1][threadIdx.x] = ss[j];
        __syncthreads();
        for (int off = 128; off >= 8; off >>= 1) {
            if (threadIdx.x < off) {
                ls[0][threadIdx.x] += ls[0][threadIdx.x + off];
                ls[1][threadIdx.x] += ls[1][threadIdx.x + off];
            }
            __syncthreads();
        }
        if (threadIdx.x < 8) {
            atomicAdd(&out[threadIdx.x * 8 + j], ls[0][threadIdx.x]);
            atomicAdd(&out[64 + threadIdx.x * 8 + j], ls[1][threadIdx.x]);
        }
        __syncthreads();
    }
}

// BN(train)+SiLU in place over bf16 [N,64], 8 elems/thread.
__global__ __launch_bounds__(256) void bnsilub_k(ushort_t* __restrict__ h,
                                                 const float* __restrict__ stats,
                                                 const float* __restrict__ gamma,
                                                 const float* __restrict__ beta,
                                                 int total8, float invN) {
    int i8 = blockIdx.x * 256 + threadIdx.x;
    if (i8 >= total8) return;
    int c0  = (i8 * 8) & 63;
    uint4 u = ((const uint4*)h)[i8];
    float f[8];
    u4tof(u, f);
#pragma unroll
    for (int j = 0; j < 8; ++j) {
        int c     = c0 + j;
        float m   = stats[c] * invN;
        float var = stats[64 + c] * invN - m * m;
        float x   = (f[j] - m) * rsqrtf(var + EPSF) * gamma[c] + beta[c];
        f[j]      = x / (1.f + expf(-x));
    }
    uint4 o;
    o.x = (uint_t)f2b(f[0]) | ((uint_t)f2b(f[1]) << 16);
    o.y = (uint_t)f2b(f[2]) | ((uint_t)f2b(f[3]) << 16);
    o.z = (uint_t)f2b(f[4]) | ((uint_t)f2b(f[5]) << 16);
    o.w = (uint_t)f2b(f[6]) | ((uint_t)f2b(f[7]) << 16);
    ((uint4*)h)[i8] = o;
}

// ---------------------------------------------------------------------------
// Point branch: trilinear gather (bf16 x) + BN+SiLU+Linear -> z1 (f32).
// Block = 4 waves over 64 points; wave w owns channels [16w,16w+16).
// ---------------------------------------------------------------------------
__global__ __launch_bounds__(256) void point_k(
    const ushort_t* __restrict__ x,     // [N,64] bf16
    const float* __restrict__ z_feats, const float* __restrict__ interp_w,
    const int* __restrict__ interp_idx, const float* __restrict__ lin_w,
    const float* __restrict__ lin_b, const float* __restrict__ pstats,
    const float* __restrict__ pgamma, const float* __restrict__ pbeta,
    float* __restrict__ z1_out, int P, float invP) {
    const int lane = threadIdx.x & 63;
    const int wv   = threadIdx.x >> 6;
    const int p    = blockIdx.x * 64 + lane;
    if (p >= P) return;
    const int wbase = __builtin_amdgcn_readfirstlane(wv * 16);

    const int4* iip   = (const int4*)(interp_idx + (size_t)p * 8);
    const float4* iwp = (const float4*)(interp_w + (size_t)p * 8);
    int4 ia = iip[0], ib = iip[1];
    float4 wa = iwp[0], wb = iwp[1];
    int idxs[8]  = {ia.x, ia.y, ia.z, ia.w, ib.x, ib.y, ib.z, ib.w};
    float wts[8] = {wa.x, wa.y, wa.z, wa.w, wb.x, wb.y, wb.z, wb.w};

    float acc[16];
#pragma unroll
    for (int o = 0; o < 16; ++o) acc[o] = 0.f;

#pragma unroll
    for (int t = 0; t < 8; ++t) {
        const ushort_t* xr = x + (size_t)idxs[t] * 64 + wbase;
        float w            = wts[t];
        uint4 u0 = *(const uint4*)xr;
        uint4 u1 = *(const uint4*)(xr + 8);
        float f[16];
        u4tof(u0, f);
        u4tof(u1, f + 8);
#pragma unroll
        for (int o = 0; o < 16; ++o) acc[o] = fmaf(w, f[o], acc[o]);
    }

    const float4* zr4 = (const float4*)(z_feats + (size_t)p * 32);
#pragma unroll
    for (int i4 = 0; i4 < 8; ++i4) {
        float4 zv = zr4[i4];
#pragma unroll
        for (int j = 0; j < 4; ++j) {
            int i     = i4 * 4 + j;
            float m   = pstats[i] * invP;
            float var = pstats[32 + i] * invP - m * m;
            float zn  = ((&zv.x)[j] - m) * rsqrtf(var + EPSF) * pgamma[i] + pbeta[i];
            float pz  = zn / (1.f + expf(-zn));
            const float* lw = lin_w + i * 64 + wbase;
#pragma unroll
            for (int o = 0; o < 16; ++o) acc[o] = fmaf(pz, lw[o], acc[o]);
        }
    }
    const float* lb = lin_b + wbase;
#pragma unroll
    for (int o = 0; o < 16; ++o) acc[o] += lb[o];

    float* zo = z1_out + (size_t)p * 64 + wbase;
#pragma unroll
    for (int o = 0; o < 16; o += 4) {
        float4 v = {acc[o], acc[o + 1], acc[o + 2], acc[o + 3]};
        *(float4*)(zo + o) = v;
    }
}

// --------------------------- CSR build + gather-average ---------------------
__global__ __launch_bounds__(256) void hist_k(const int* __restrict__ p2v,
                                              int* __restrict__ cnt, int P) {
    int p = blockIdx.x * 256 + threadIdx.x;
    if (p < P) atomicAdd(&cnt[p2v[p]], 1);
}

__global__ __launch_bounds__(256) void scan1_k(const int* __restrict__ cnt,
                                               int* __restrict__ tmp,
                                               int* __restrict__ bsum, int n) {
    __shared__ int s[256];
    int i = blockIdx.x * 256 + threadIdx.x;
    int v = (i < n) ? cnt[i] : 0;
    s[threadIdx.x] = v;
    __syncthreads();
    for (int off = 1; off < 256; off <<= 1) {
        int t = (threadIdx.x >= off) ? s[threadIdx.x - off] : 0;
        __syncthreads();
        s[threadIdx.x] += t;
        __syncthreads();
    }
    if (i < n) tmp[i] = s[threadIdx.x];
    if (threadIdx.x == 255) bsum[blockIdx.x] = s[255];
}

__global__ void scan2_k(const int* __restrict__ bsum, int* __restrict__ bpre,
                        int nb) {
    if (blockIdx.x == 0 && threadIdx.x == 0) {
        int a = 0;
        for (int b = 0; b < nb; ++b) { bpre[b] = a; a += bsum[b]; }
    }
}

__global__ __launch_bounds__(256) void scan3_k(const int* __restrict__ cnt,
                                               const int* __restrict__ tmp,
                                               const int* __restrict__ bpre,
                                               int* __restrict__ off, int n) {
    int i = blockIdx.x * 256 + threadIdx.x;
    if (i < n) off[i] = bpre[i >> 8] + tmp[i] - cnt[i];
}

__global__ __launch_bounds__(256) void fill_k(const int* __restrict__ p2v,
                                              const int* __restrict__ off,
                                              int* __restrict__ cursor,
                                              int* __restrict__ bucket, int P) {
    int p = blockIdx.x * 256 + threadIdx.x;
    if (p >= P) return;
    int v    = p2v[p];
    int slot = atomicAdd(&cursor[v], 1);
    bucket[off[v] + slot] = p;
}

// x_new[v] = mean of z1 rows of points in voxel v. Thread = (voxel, quarter).
__global__ __launch_bounds__(256) void avg_k(const float* __restrict__ z1,
                                             const int* __restrict__ off,
                                             const int* __restrict__ cnt,
                                             const int* __restrict__ bucket,
                                             float* __restrict__ xnew, int N) {
    int tid = blockIdx.x * 256 + threadIdx.x;
    int v   = tid >> 2;
    if (v >= N) return;
    int q  = tid & 3;
    int c  = cnt[v];
    int st = off[v];
    float acc[16];
#pragma unroll
    for (int o = 0; o < 16; ++o) acc[o] = 0.f;
    for (int j = 0; j < c; ++j) {
        int p            = bucket[st + j];
        const float4* zr = (const float4*)(z1 + (size_t)p * 64 + q * 16);
#pragma unroll
        for (int c4 = 0; c4 < 4; ++c4) {
            float4 t = zr[c4];
            acc[c4 * 4 + 0] += t.x;
            acc[c4 * 4 + 1] += t.y;
            acc[c4 * 4 + 2] += t.z;
            acc[c4 * 4 + 3] += t.w;
        }
    }
    float rc  = 1.f / fmaxf((float)c, 1.f);
    float* op = xnew + (size_t)v * 64 + q * 16;
#pragma unroll
    for (int o = 0; o < 16; o += 4) {
        float4 t = {acc[o] * rc, acc[o + 1] * rc, acc[o + 2] * rc, acc[o + 3] * rc};
        *(float4*)(op + o) = t;
    }
}

extern "C" void kernel_launch(void* const* d_in, const int* in_sizes, int n_in,
                              void* d_out, int out_size, void* d_ws, size_t ws_size,
                              hipStream_t stream) {
    const float* x_feats   = (const float*)d_in[0];
    const float* z_feats   = (const float*)d_in[1];
    const float* interp_w  = (const float*)d_in[2];
    const int* nbr_idx     = (const int*)d_in[3];
    const int* interp_idx  = (const int*)d_in[4];
    const int* p2v_idx     = (const int*)d_in[5];
    const float* conv1_w   = (const float*)d_in[6];
    const float* conv2_w   = (const float*)d_in[7];
    const float* bn_gamma  = (const float*)d_in[8];
    const float* bn_beta   = (const float*)d_in[9];
    const float* pbn_gamma = (const float*)d_in[10];
    const float* pbn_beta  = (const float*)d_in[11];
    const float* lin_w     = (const float*)d_in[12];
    const float* lin_b     = (const float*)d_in[13];

    const int N  = in_sizes[3] / KOFF;  // 100000
    const int P  = in_sizes[5];         // 200000
    const int NB = (N + 255) / 256;

    // Workspace layout
    ushort_t* h2   = (ushort_t*)d_ws;                 // [N*64] bf16
    ushort_t* xb   = h2 + (size_t)N * 64;             // [N*64] bf16 (conv2 out)
    ushort_t* xf16 = xb + (size_t)N * 64;             // [N*32] bf16
    ushort_t* wt1  = xf16 + (size_t)N * 32;           // [27*64*32]
    ushort_t* wt2  = wt1 + KOFF * 64 * 32;            // [27*64*64]
    int* cnt       = (int*)(wt2 + KOFF * 64 * 64);    // [N]
    int* cursor    = cnt + N;                         // [N]
    float* stats   = (float*)(cursor + N);            // [192]: h 128 | p 64
    int* tmp       = (int*)(stats + 192);             // [N]
    int* off       = tmp + N;                         // [N]
    int* bsum      = off + N;                         // [512]
    int* bpre      = bsum + 512;                      // [512]
    int* bucket    = bpre + 512;                      // [P]
    float* stats_h = stats;
    float* stats_p = stats + 128;

    float* xnew = (float*)d_out;             // [N,64]
    float* z1   = xnew + (size_t)N * 64;     // [P,64]

    // Zero cnt, cursor, stats (contiguous).
    hipMemsetAsync(cnt, 0, ((size_t)2 * N + 192) * sizeof(int), stream);

    // Input conversions (f32 -> bf16) + weight transpose.
    cvt_k<<<((size_t)N * 32 / 8 + 255) / 256, 256, 0, stream>>>(x_feats, xf16,
                                                                N * 32 / 8);
    wtT_k<<<(KOFF * 32 * 64 + 255) / 256, 256, 0, stream>>>(conv1_w, wt1, 32);
    wtT_k<<<(KOFF * 64 * 64 + 255) / 256, 256, 0, stream>>>(conv2_w, wt2, 64);

    // CSR build.
    hist_k<<<(P + 255) / 256, 256, 0, stream>>>(p2v_idx, cnt, P);
    scan1_k<<<NB, 256, 0, stream>>>(cnt, tmp, bsum, N);
    scan2_k<<<1, 1, 0, stream>>>(bsum, bpre, NB);
    scan3_k<<<NB, 256, 0, stream>>>(cnt, tmp, bpre, off, N);
    fill_k<<<(P + 255) / 256, 256, 0, stream>>>(p2v_idx, off, cursor, bucket, P);

    // Point-branch BN stats (f32 z_feats).
    stats_k<32><<<256, 256, 0, stream>>>(z_feats, P, stats_p);

    // conv1 (MFMA): xf16 -> h2 (bf16)
    convm_k<32, true><<<(N + 63) / 64, 256, 0, stream>>>(xf16, nbr_idx, wt1, h2, N);

    // BN stats over h2, then BN+SiLU in place (bf16).
    statsb_k<<<512, 256, 0, stream>>>(h2, N, stats_h);
    bnsilub_k<<<((size_t)N * 64 / 8 + 255) / 256, 256, 0, stream>>>(
        h2, stats_h, bn_gamma, bn_beta, N * 64 / 8, 1.f / (float)N);

    // conv2 (MFMA): h2 -> xb (bf16)
    convm_k<64, true><<<(N + 63) / 64, 256, 0, stream>>>(h2, nbr_idx, wt2, xb, N);

    // Point branch -> z1 (f32).
    point_k<<<(P + 63) / 64, 256, 0, stream>>>(xb, z_feats, interp_w, interp_idx,
                                               lin_w, lin_b, stats_p, pbn_gamma,
                                               pbn_beta, z1, P, 1.f / (float)P);

    // Gather-average into x_new.
    avg_k<<<((size_t)N * 4 + 255) / 256, 256, 0, stream>>>(z1, off, cnt, bucket,
                                                           xnew, N);

    (void)n_in; (void)out_size; (void)ws_size;
}